// Round 8
// baseline (1830.278 us; speedup 1.0000x reference)
//
#include <hip/hip_runtime.h>
#include <hip/hip_bf16.h>
#include <cstdint>
#include <cstddef>

// Problem dims
#define SS   512
#define BB   64
#define EMBD 512
#define HIDD 512
#define MAXD 1024
#define NCLS 20
#define KCAT 1536
#define ROWS (SS*BB)   // 32768

// ---------- small helpers ----------
__device__ __forceinline__ uint16_t f2bf(float f) {
  uint32_t u = __float_as_uint(f);
  uint32_t r = u + 0x7fffu + ((u >> 16) & 1u);
  return (uint16_t)(r >> 16);
}
__device__ __forceinline__ float bf2f(uint32_t h) {
  return __uint_as_float(h << 16);
}
__device__ __forceinline__ uint32_t pk2(float a, float b) {
  return (uint32_t)f2bf(a) | ((uint32_t)f2bf(b) << 16);
}

// fast tanh: (1-e^{-2|x|})/(1+e^{-2|x|}) with native exp2/rcp, sign restore.
__device__ __forceinline__ float fast_tanh(float x) {
  float ax = __builtin_fabsf(x);
  float e  = __builtin_amdgcn_exp2f(ax * -2.885390081777927f);  // e^{-2ax}
  float r  = (1.f - e) * __builtin_amdgcn_rcpf(1.f + e);
  return __builtin_copysignf(r, x);
}

__device__ __forceinline__ void gl_lds16(const void* g, void* l) {
  __builtin_amdgcn_global_load_lds((const __attribute__((address_space(1))) void*)g,
                                   (__attribute__((address_space(3))) void*)l,
                                   16, 0, 0);
}

typedef short v8s __attribute__((ext_vector_type(8)));
typedef float v4f __attribute__((ext_vector_type(4)));

// ---------- K0: gather emb -> cat[:,512:1024] (bf16), convert weights to bf16 ----------
__global__ __launch_bounds__(256) void prep_kernel(
    const int* __restrict__ inp, const float* __restrict__ table,
    const float* __restrict__ Wsl, const float* __restrict__ Wsr,
    const float* __restrict__ Wl,  const float* __restrict__ Wr,
    const float* __restrict__ Wmax,
    uint16_t* __restrict__ cat, uint16_t* __restrict__ wslb,
    uint16_t* __restrict__ wsrb, uint16_t* __restrict__ wlb,
    uint16_t* __restrict__ wrb, uint16_t* __restrict__ wmaxb)
{
  const int blk = blockIdx.x, t = threadIdx.x;
  if (blk < 8192) {
    const int r = blk * 4 + (t >> 6);
    const int lane = t & 63;
    const int token = inp[r];
    const float4* src = (const float4*)(table + (size_t)token * EMBD);
    uint16_t* dst = cat + (size_t)r * KCAT + 512;
#pragma unroll
    for (int p = 0; p < 2; ++p) {
      const int slot = lane + 64 * p;   // 0..127 float4 slots per row
      float4 v = src[slot];
      uint2 o;
      o.x = pk2(v.x, v.y);
      o.y = pk2(v.z, v.w);
      *(uint2*)(dst + slot * 4) = o;
    }
  } else {
    size_t flat = (size_t)(blk - 8192) * 2048 + (size_t)t * 8;
    const float* src; uint16_t* dst; size_t off;
    if (flat < 262144)       { src = Wsl;  dst = wslb;  off = flat; }
    else if (flat < 524288)  { src = Wsr;  dst = wsrb;  off = flat - 262144; }
    else if (flat < 786432)  { src = Wl;   dst = wlb;   off = flat - 524288; }
    else if (flat < 1048576) { src = Wr;   dst = wrb;   off = flat - 786432; }
    else                     { src = Wmax; dst = wmaxb; off = flat - 1048576; }
    float4 v0 = *(const float4*)(src + off);
    float4 v1 = *(const float4*)(src + off + 4);
    uint4 o;
    o.x = pk2(v0.x, v0.y); o.y = pk2(v0.z, v0.w);
    o.z = pk2(v1.x, v1.y); o.w = pk2(v1.z, v1.w);
    *(uint4*)(dst + off) = o;
  }
}

// ---------- GEMM (m97-style): C[M x 1024] = A[M x K] @ W^T, 128x128 tiles, BK=64 ----------
// MODE 0: out = A@W^T + bias -> bf16 store (proj GEMM, W split at n=512)
// MODE 1: v = tanh(A@W^T + bias); partial[mb][b][n] = max over the block's 2 s-rows
template<int MODE>
__global__ __launch_bounds__(256, 2) void gemm_kernel(
    const uint16_t* __restrict__ A, int lda, int K,
    const uint16_t* __restrict__ W0, const uint16_t* __restrict__ W1,
    const float* __restrict__ bias0, const float* __restrict__ bias1,
    uint16_t* __restrict__ outb, float* __restrict__ partial)
{
  __shared__ unsigned char smem[32768];
  uint16_t* lA = (uint16_t*)smem;            // 128x64 bf16 = 16 KB
  uint16_t* lW = (uint16_t*)(smem + 16384);  // 128x64 bf16 = 16 KB

  const int tid = threadIdx.x;
  const int mb = blockIdx.x, nb = blockIdx.y;
  const int m0 = mb * 128, n0 = nb * 128;

  const uint16_t* Wp = W0;
  const float* biasp = bias0;
  int nr0 = n0;
  if (MODE == 0 && n0 >= 512) { Wp = W1; biasp = bias1; nr0 = n0 - 512; }

  const int w = tid >> 6, lane = tid & 63;
  const int mw = w & 1, nw = w >> 1;

  v4f acc[4][4];
#pragma unroll
  for (int i = 0; i < 4; ++i)
#pragma unroll
    for (int j = 0; j < 4; ++j) {
      v4f z = {0.f, 0.f, 0.f, 0.f};
      acc[i][j] = z;
    }

  const int r_st = tid >> 3;   // + p*32
  const int u_st = tid & 7;

  for (int kk = 0; kk < K; kk += 64) {
    __syncthreads();
#pragma unroll
    for (int p = 0; p < 4; ++p) {
      const int r = p * 32 + r_st;
      gl_lds16(A + (size_t)(m0 + r) * lda + kk + u_st * 8, lA + (p * 256 + tid) * 8);
    }
#pragma unroll
    for (int p = 0; p < 4; ++p) {
      const int r = p * 32 + r_st;
      gl_lds16(Wp + (size_t)(nr0 + r) * K + kk + u_st * 8, lW + (p * 256 + tid) * 8);
    }
    __syncthreads();
#pragma unroll
    for (int ks = 0; ks < 2; ++ks) {
      v8s af[4], wf[4];
#pragma unroll
      for (int i = 0; i < 4; ++i)
        af[i] = *(const v8s*)&lA[(mw * 64 + i * 16 + (lane & 15)) * 64 + ks * 32 + (lane >> 4) * 8];
#pragma unroll
      for (int j = 0; j < 4; ++j)
        wf[j] = *(const v8s*)&lW[(nw * 64 + j * 16 + (lane & 15)) * 64 + ks * 32 + (lane >> 4) * 8];
#pragma unroll
      for (int i = 0; i < 4; ++i)
#pragma unroll
        for (int j = 0; j < 4; ++j)
          acc[i][j] = __builtin_amdgcn_mfma_f32_16x16x32_bf16(af[i], wf[j], acc[i][j], 0, 0, 0);
    }
  }

  __syncthreads();  // all LDS frag reads done before epilogue reuse

  if (MODE == 0) {
#pragma unroll
    for (int i = 0; i < 4; ++i)
#pragma unroll
      for (int j = 0; j < 4; ++j) {
        const int nl = nw * 64 + j * 16 + (lane & 15);
        const float bv = biasp[nr0 + nl];
        const int colg = n0 + nl;
#pragma unroll
        for (int r = 0; r < 4; ++r) {
          const int rowg = m0 + mw * 64 + i * 16 + (lane >> 4) * 4 + r;
          outb[(size_t)rowg * 1024 + colg] = f2bf(acc[i][j][r] + bv);
        }
      }
  } else {
    float* lred = (float*)smem;   // 64 b x 128 n f32 = 32 KB
    if (mw == 1) {
#pragma unroll
      for (int i = 0; i < 4; ++i)
#pragma unroll
        for (int j = 0; j < 4; ++j) {
          const int nl = nw * 64 + j * 16 + (lane & 15);
          const float bv = biasp[nr0 + nl];
#pragma unroll
          for (int r = 0; r < 4; ++r) {
            const int bl = i * 16 + (lane >> 4) * 4 + r;
            lred[bl * 128 + nl] = fast_tanh(acc[i][j][r] + bv);
          }
        }
    }
    __syncthreads();
    if (mw == 0) {
#pragma unroll
      for (int i = 0; i < 4; ++i)
#pragma unroll
        for (int j = 0; j < 4; ++j) {
          const int nl = nw * 64 + j * 16 + (lane & 15);
          const float bv = biasp[nr0 + nl];
#pragma unroll
          for (int r = 0; r < 4; ++r) {
            const int bl = i * 16 + (lane >> 4) * 4 + r;
            const float v = fast_tanh(acc[i][j][r] + bv);
            partial[((size_t)mb * 64 + bl) * 1024 + n0 + nl] = fmaxf(v, lred[bl * 128 + nl]);
          }
        }
    }
  }
}

// ---------- K2: MFMA recurrence scan ----------
// R3 (643us) was dot2-ISSUE-bound: 128 dot2/thread at ~quarter rate = ~2050 of
// the 3010 cyc step (fit: R4 readlane +35us, R2->R3 -580cyc both consistent).
// The dot is matmul-shaped once batches are blocked -> move it to the MFMA pipe.
// 16 blocks = 4 batch-groups(16) x 2 dirs x 2 h-halves; bid = half*8+g*2+d;
// partner = bid^8 (same bid%8 -> same XCD L2).
// Per block: C[16 batch x 256 h] = A[16 x 512] @ W_half^T per step.
//  * W fragments in regs (32 x v8s, loop-invariant; exact gemm-verified layout:
//    lane reads W[n=tile+lane&15][k=kt*32+(lane>>4)*8 ..+8]).
//  * A (c state, 16 batch x 512 k bf16) in LDS, parity double-buffered,
//    chunk-XOR swizzled: byte(batch,chunk)=(batch*64+(chunk^(batch&7)))*16 ->
//    MFMA A-frag reads are 2-way max (free).
//  * step: [cat readback (pipelined 1 behind)] -> 16 ds_read_b128 + 32 MFMA
//    (2 N-tiles x 16 K-tiles, 4 indep acc chains) -> finalize 8 vals/thread
//    (bias + e + fast_tanh) -> publish 4 u64 seq|2xbf16 packets (proven
//    protocol/parity/poison) -> own A-next writes -> sched_barrier (publish
//    before poll pin, R5 lesson) -> poll partner's 4 mirror packets (bijection:
//    partner's h == my h) -> ONE barrier.
//  * e prefetched 2 steps ahead into regs (erA/erB, compile-time selected via
//    2x-unrolled loop -- rule #20).
__global__ __launch_bounds__(512, 1) void scan_kernel(
    const uint16_t* __restrict__ ee,     // [32768][1024] bf16: ls | rs
    const uint16_t* __restrict__ wlb, const uint16_t* __restrict__ wrb,
    const float* __restrict__ bl, const float* __restrict__ br,
    const float* __restrict__ cl0, const float* __restrict__ cr0,
    uint16_t* __restrict__ cat,
    uint64_t* __restrict__ cbuf)
{
  const int tid = threadIdx.x;
  const int bid = blockIdx.x;
  const int half = bid >> 3;          // h-half
  const int g    = (bid >> 1) & 3;    // batch group
  const int d    = bid & 1;           // direction
  const int bg   = g * 16;
  const int pbid = bid ^ 8;

  const int w    = tid >> 6;          // wave 0..7
  const int lane = tid & 63;
  const int m4   = (lane >> 4) * 4;   // C-row (batch) base for this lane
  const int ncol = lane & 15;         // C-col within tile
  const int h0   = half * 256 + w * 32 + ncol;        // N-tile 0 column (k index)
  const int h1   = h0 + 16;                            // N-tile 1
  const int ph0  = (1 - half) * 256 + w * 32 + ncol;   // partner's h0 == mirror
  const int ph1  = ph0 + 16;

  // A state: [parity][16 batch][512 k] bf16, swizzled chunks (16B units)
  __shared__ __align__(16) uint16_t Abuf[2][8192];

#define SWZ(batch, chunk) ((((batch) * 64) + ((chunk) ^ ((batch) & 7))) * 16)

  const uint16_t* wsrc = d ? wrb : wlb;

  // ---- W fragments (loop-invariant) ----
  v8s wf0[16], wf1[16];
  {
    const uint16_t* p0 = wsrc + (size_t)h0 * 512 + (lane >> 4) * 8;
    const uint16_t* p1 = wsrc + (size_t)h1 * 512 + (lane >> 4) * 8;
#pragma unroll
    for (int kt = 0; kt < 16; ++kt) {
      wf0[kt] = *(const v8s*)(p0 + kt * 32);
      wf1[kt] = *(const v8s*)(p1 + kt * 32);
    }
  }

  // ---- A init: c0 broadcast to 16 batches ----
  {
    const float* c0v = d ? cr0 : cl0;
    const int batch = tid >> 5;
#pragma unroll
    for (int cc = 0; cc < 2; ++cc) {
      const int chunk = (tid & 31) * 2 + cc;   // global k-chunk 0..63
      const float* src = c0v + chunk * 8;
      uint4 o;
      o.x = pk2(src[0], src[1]); o.y = pk2(src[2], src[3]);
      o.z = pk2(src[4], src[5]); o.w = pk2(src[6], src[7]);
      *(uint4*)((char*)Abuf[0] + SWZ(batch, chunk)) = o;
    }
  }

  const float* bvec = d ? br : bl;
  const float bias0v = bvec[h0];
  const float bias1v = bvec[h1];

  // ---- e prefetch rings (2 steps ahead; even steps use erA, odd erB) ----
  const int ec0 = d * 512 + h0, ec1 = d * 512 + h1;
  uint32_t erA[8], erB[8];
  {
    const int s0 = d ? 511 : 0, s1 = d ? 510 : 1;
#pragma unroll
    for (int r = 0; r < 4; ++r) {
      erA[r]     = *(const uint16_t*)&ee[(size_t)(s0 * 64 + bg + m4 + r) * 1024 + ec0];
      erA[4 + r] = *(const uint16_t*)&ee[(size_t)(s0 * 64 + bg + m4 + r) * 1024 + ec1];
      erB[r]     = *(const uint16_t*)&ee[(size_t)(s1 * 64 + bg + m4 + r) * 1024 + ec0];
      erB[4 + r] = *(const uint16_t*)&ee[(size_t)(s1 * 64 + bg + m4 + r) * 1024 + ec1];
    }
  }

  const int catbase = (d ? 1024 : 0) + half * 256;
  const int rbBatch = tid >> 5, rbCl = tid & 31;   // cat readback geometry
  const int rbChunk = half * 32 + rbCl;

  __syncthreads();

  // step body; er bound at compile time (erA even / erB odd)
  auto step = [&](int i, uint32_t (&er)[8]) {
    // cat writeback for step i-1 (its c lives in Abuf[i&1])
    if (i > 0) {
      const int sP = d ? (512 - i) : (i - 1);
      uint4 v = *(const uint4*)((char*)Abuf[i & 1] + SWZ(rbBatch, rbChunk));
      *(uint4*)&cat[(size_t)(sP * 64 + bg + rbBatch) * KCAT + catbase + rbCl * 8] = v;
    }

    // MFMA: 2 N-tiles x 16 K-tiles, 4 independent chains
    v4f a00 = {0.f, 0.f, 0.f, 0.f}, a01 = {0.f, 0.f, 0.f, 0.f};
    v4f a10 = {0.f, 0.f, 0.f, 0.f}, a11 = {0.f, 0.f, 0.f, 0.f};
#pragma unroll
    for (int kt = 0; kt < 16; ++kt) {
      v8s af = *(const v8s*)((char*)Abuf[i & 1] + SWZ(lane & 15, kt * 4 + (lane >> 4)));
      if (kt & 1) {
        a01 = __builtin_amdgcn_mfma_f32_16x16x32_bf16(af, wf0[kt], a01, 0, 0, 0);
        a11 = __builtin_amdgcn_mfma_f32_16x16x32_bf16(af, wf1[kt], a11, 0, 0, 0);
      } else {
        a00 = __builtin_amdgcn_mfma_f32_16x16x32_bf16(af, wf0[kt], a00, 0, 0, 0);
        a10 = __builtin_amdgcn_mfma_f32_16x16x32_bf16(af, wf1[kt], a10, 0, 0, 0);
      }
    }

    // finalize: 8 values (4 batches x 2 h)
    float v0[4], v1[4];
#pragma unroll
    for (int r = 0; r < 4; ++r) {
      v0[r] = fast_tanh(a00[r] + a01[r] + bias0v + bf2f(er[r]));
      v1[r] = fast_tanh(a10[r] + a11[r] + bias1v + bf2f(er[4 + r]));
    }

    // reissue e loads for step i+2 (same regs; consumed 2 steps later)
    if (i < 510) {
      const int s2 = d ? (509 - i) : (i + 2);
#pragma unroll
      for (int r = 0; r < 4; ++r) {
        er[r]     = *(const uint16_t*)&ee[(size_t)(s2 * 64 + bg + m4 + r) * 1024 + ec0];
        er[4 + r] = *(const uint16_t*)&ee[(size_t)(s2 * 64 + bg + m4 + r) * 1024 + ec1];
      }
    }

    char* An = (char*)Abuf[(i + 1) & 1];
    if (i != 511) {
      const uint64_t want = (uint64_t)(uint32_t)(i + 1);
      // publish FIRST (partner's poll is the critical consumer)
#pragma unroll
      for (int r = 0; r < 4; ++r) {
        uint64_t pkt = (want << 32) | (uint64_t)pk2(v0[r], v1[r]);
        __hip_atomic_store(&cbuf[(size_t)(((i & 1) * 16 + bid) * 2048 + tid * 4 + r)],
                           pkt, __ATOMIC_RELAXED, __HIP_MEMORY_SCOPE_AGENT);
      }
      // own half of A-next
#pragma unroll
      for (int r = 0; r < 4; ++r) {
        *(uint16_t*)(An + SWZ(m4 + r, h0 >> 3) + (h0 & 7) * 2) = f2bf(v0[r]);
        *(uint16_t*)(An + SWZ(m4 + r, h1 >> 3) + (h1 & 7) * 2) = f2bf(v1[r]);
      }
      // pin publish before the spin (same-wave store->spin hazard, R5 lesson)
      __builtin_amdgcn_sched_barrier(0);
      // poll partner's mirror packets -> remote half of A-next
#pragma unroll
      for (int r = 0; r < 4; ++r) {
        const uint64_t* slot =
            &cbuf[(size_t)(((i & 1) * 16 + pbid) * 2048 + tid * 4 + r)];
        uint64_t v = __hip_atomic_load(slot, __ATOMIC_RELAXED, __HIP_MEMORY_SCOPE_AGENT);
        while ((v >> 32) != want) {
          __builtin_amdgcn_s_sleep(1);
          v = __hip_atomic_load(slot, __ATOMIC_RELAXED, __HIP_MEMORY_SCOPE_AGENT);
        }
        *(uint16_t*)(An + SWZ(m4 + r, ph0 >> 3) + (ph0 & 7) * 2) = (uint16_t)(v & 0xffffu);
        *(uint16_t*)(An + SWZ(m4 + r, ph1 >> 3) + (ph1 & 7) * 2) = (uint16_t)((v >> 16) & 0xffffu);
      }
      __syncthreads();   // A-next (own + remote) complete before next dot
    } else {
      // last step: only our own half is needed (for the cat flush)
#pragma unroll
      for (int r = 0; r < 4; ++r) {
        *(uint16_t*)(An + SWZ(m4 + r, h0 >> 3) + (h0 & 7) * 2) = f2bf(v0[r]);
        *(uint16_t*)(An + SWZ(m4 + r, h1 >> 3) + (h1 & 7) * 2) = f2bf(v1[r]);
      }
    }
  };

  for (int ii = 0; ii < 256; ++ii) {
    step(2 * ii, erA);
    step(2 * ii + 1, erB);
  }

  // flush cat for the final step (c@s(511) lives in Abuf[0])
  __syncthreads();
  {
    const int sL = d ? 0 : 511;
    uint4 v = *(const uint4*)((char*)Abuf[0] + SWZ(rbBatch, rbChunk));
    *(uint4*)&cat[(size_t)(sL * 64 + bg + rbBatch) * KCAT + catbase + rbCl * 8] = v;
  }
#undef SWZ
}

// ---------- K4: max-reduce partials, classifier, log_softmax ----------
__global__ __launch_bounds__(256) void final_kernel(
    const float* __restrict__ partial, const float* __restrict__ Wdoc,
    const float* __restrict__ bdoc, float* __restrict__ out)
{
  const int b = blockIdx.x, t = threadIdx.x;
  __shared__ float ym[1024];
  __shared__ float lg[32];
  float m0 = -2.f, m1 = -2.f, m2 = -2.f, m3 = -2.f;
  for (int mg = 0; mg < 256; ++mg) {
    const float* p = partial + ((size_t)mg * 64 + b) * 1024;
    m0 = fmaxf(m0, p[t]);
    m1 = fmaxf(m1, p[t + 256]);
    m2 = fmaxf(m2, p[t + 512]);
    m3 = fmaxf(m3, p[t + 768]);
  }
  ym[t] = m0; ym[t + 256] = m1; ym[t + 512] = m2; ym[t + 768] = m3;
  __syncthreads();
  if (t < NCLS) {
    const float* wr = Wdoc + (size_t)t * 1024;
    float a0 = 0.f, a1 = 0.f, a2 = 0.f, a3 = 0.f;
    for (int n = 0; n < 1024; n += 4) {
      a0 = fmaf(ym[n], wr[n], a0);
      a1 = fmaf(ym[n + 1], wr[n + 1], a1);
      a2 = fmaf(ym[n + 2], wr[n + 2], a2);
      a3 = fmaf(ym[n + 3], wr[n + 3], a3);
    }
    lg[t] = (a0 + a1) + (a2 + a3) + bdoc[t];
  }
  __syncthreads();
  if (t < NCLS) {
    float mx = -1e30f;
    for (int c = 0; c < NCLS; ++c) mx = fmaxf(mx, lg[c]);
    float ssum = 0.f;
    for (int c = 0; c < NCLS; ++c) ssum += expf(lg[c] - mx);
    out[b * NCLS + t] = lg[t] - mx - logf(ssum);
  }
}

// ---------- launch ----------
extern "C" void kernel_launch(void* const* d_in, const int* in_sizes, int n_in,
                              void* d_out, int out_size, void* d_ws, size_t ws_size,
                              hipStream_t stream) {
  const int*   inp   = (const int*)  d_in[0];
  const float* table = (const float*)d_in[1];
  const float* cl0   = (const float*)d_in[2];
  const float* cr0   = (const float*)d_in[3];
  const float* Wl    = (const float*)d_in[4];
  const float* bl    = (const float*)d_in[5];
  const float* Wr    = (const float*)d_in[6];
  const float* br    = (const float*)d_in[7];
  const float* Wsl   = (const float*)d_in[8];
  const float* bsl   = (const float*)d_in[9];
  const float* Wsr   = (const float*)d_in[10];
  const float* bsr   = (const float*)d_in[11];
  const float* Wmax  = (const float*)d_in[12];
  const float* bmax  = (const float*)d_in[13];
  const float* Wdoc  = (const float*)d_in[14];
  const float* bdoc  = (const float*)d_in[15];

  uint8_t* ws = (uint8_t*)d_ws;
  uint16_t* cat     = (uint16_t*)(ws);                 // 32768*1536*2 = 100663296
  uint16_t* ee      = (uint16_t*)(ws + 100663296);     // 32768*1024*2 = 67108864
  float*    partial = (float*)   (ws + 167772160);     // 256*64*1024*4 = 67108864
  uint16_t* wslb    = (uint16_t*)(ws + 234881024);     // 524288
  uint16_t* wsrb    = (uint16_t*)(ws + 235405312);     // 524288
  uint16_t* wmaxb   = (uint16_t*)(ws + 235929600);     // 3145728
  uint16_t* wlb     = (uint16_t*)(ws + 239075328);     // 524288
  uint16_t* wrb     = (uint16_t*)(ws + 239599616);     // 524288
  // cbuf (u64 seq|payload, 2 parity x 16 bid x 2048 slots = 512 KB) overlays the
  // START of `partial`: poisoned 0xAA at launch (seq never matches), and gemm<1>
  // fully overwrites partial AFTER the scan completes. No ws growth.
  uint64_t* cbuf    = (uint64_t*)(ws + 167772160);

  prep_kernel<<<9472, 256, 0, stream>>>(inp, table, Wsl, Wsr, Wl, Wr, Wmax,
                                        cat, wslb, wsrb, wlb, wrb, wmaxb);
  gemm_kernel<0><<<dim3(256, 8), 256, 0, stream>>>(cat + 512, KCAT, 512, wslb, wsrb,
                                                   bsl, bsr, ee, nullptr);
  scan_kernel<<<16, 512, 0, stream>>>(ee, wlb, wrb, bl, br, cl0, cr0, cat, cbuf);
  gemm_kernel<1><<<dim3(256, 8), 256, 0, stream>>>(cat, KCAT, KCAT, wmaxb, nullptr,
                                                   bmax, nullptr, nullptr, partial);
  final_kernel<<<64, 256, 0, stream>>>(partial, Wdoc, bdoc, (float*)d_out);
}